// Round 1
// baseline (878.818 us; speedup 1.0000x reference)
//
#include <hip/hip_runtime.h>
#include <stdint.h>
#include <stddef.h>

#define N_ROWS 262144
#define CCH    256
#define NGRP   4096

typedef short bf16x8 __attribute__((ext_vector_type(8)));
typedef short bf16x4 __attribute__((ext_vector_type(4)));
typedef float f32x4  __attribute__((ext_vector_type(4)));
typedef int   i32x4  __attribute__((ext_vector_type(4)));

static __device__ __forceinline__ short f2bf(float f){
  union { float f; unsigned u; } v; v.f = f;
  unsigned u = v.u;
  unsigned r = (u + 0x7FFFu + ((u >> 16) & 1u)) >> 16;   // round-to-nearest-even
  return (short)r;
}

// ---- cast Wf/Wg to bf16; build Wh transpose (wht[k][j] = Wh[j][k]) ----
__global__ __launch_bounds__(256) void k_castw(
    const float* __restrict__ Wf, const float* __restrict__ Wg,
    const float* __restrict__ Wh,
    short* __restrict__ wfb, short* __restrict__ wgb, float* __restrict__ wht)
{
  int e = blockIdx.x * 256 + threadIdx.x;           // 65536 exact
  wfb[e] = f2bf(Wf[e]);
  wgb[e] = f2bf(Wg[e]);
  int k = e >> 8, j = e & 255;
  wht[e] = Wh[j * 256 + k];
}

// ---- histogram of group ids ----
__global__ __launch_bounds__(256) void k_hist(const int* __restrict__ ix, int* __restrict__ counts){
  int i = blockIdx.x * blockDim.x + threadIdx.x;
  int stride = gridDim.x * blockDim.x;
  for (; i < N_ROWS; i += stride) atomicAdd(&counts[ix[i]], 1);
}

// ---- exclusive prefix sum over 4096 counts -> cursor ----
__global__ __launch_bounds__(1024) void k_scan(const int* __restrict__ counts, int* __restrict__ cursor){
  __shared__ int sums[1024];
  int t = threadIdx.x;
  int base = t * 4;
  int c0 = counts[base], c1 = counts[base+1], c2 = counts[base+2], c3 = counts[base+3];
  sums[t] = c0 + c1 + c2 + c3;
  __syncthreads();
  for (int off = 1; off < 1024; off <<= 1){
    int v = (t >= off) ? sums[t - off] : 0;
    __syncthreads();
    sums[t] += v;
    __syncthreads();
  }
  int prev = (t == 0) ? 0 : sums[t - 1];
  cursor[base]   = prev;
  cursor[base+1] = prev + c0;
  cursor[base+2] = prev + c0 + c1;
  cursor[base+3] = prev + c0 + c1 + c2;
}

// ---- scatter: counting-sort row indices by group ----
__global__ __launch_bounds__(256) void k_scatter(const int* __restrict__ ix, int* __restrict__ cursor,
                                                 int* __restrict__ order, int* __restrict__ gid){
  int i = blockIdx.x * blockDim.x + threadIdx.x;
  int stride = gridDim.x * blockDim.x;
  for (; i < N_ROWS; i += stride){
    int g = ix[i];
    int p = atomicAdd(&cursor[g], 1);
    order[p] = i;
    gid[p] = g;
  }
}

// ---- fused GEMM (fx & gx) + exp + segment reduce ----
// block: 64 sorted rows x 128 cols, both weight matrices; 4 waves, each 16 rows.
struct Stage { short xs[64][72]; short ws[2][128][72]; };   // +8 bf16 pad -> 2-way LDS alias only
struct Epi   { float ps[32][132]; float es[32][132]; };     // +4 f32 pad  -> 2-way
union SMem { Stage st; Epi ep; };

__global__ __launch_bounds__(256) void k_gemm(
    const float* __restrict__ x,
    const short* __restrict__ wfb, const short* __restrict__ wgb,
    const float* __restrict__ bf, const float* __restrict__ bg,
    const int* __restrict__ order, const int* __restrict__ gid,
    float* __restrict__ numer, float* __restrict__ denom)
{
  __shared__ SMem sm;
  __shared__ int ord_s[64];
  __shared__ int gid_s[64];

  const int tid  = threadIdx.x;
  const int wave = tid >> 6;
  const int lane = tid & 63;
  const int l16  = lane & 15;
  const int quad = lane >> 4;

  const int r0 = blockIdx.x * 64;     // sorted-row base
  const int j0 = blockIdx.y * 128;    // output-column base

  if (tid < 64){ ord_s[tid] = order[r0 + tid]; gid_s[tid] = gid[r0 + tid]; }
  __syncthreads();

  f32x4 accF[8], accG[8];
  #pragma unroll
  for (int t = 0; t < 8; ++t){
    accF[t] = (f32x4){0.f,0.f,0.f,0.f};
    accG[t] = (f32x4){0.f,0.f,0.f,0.f};
  }

  const int xrow = tid >> 4;            // 16 threads/row, 16 rows/pass
  const int xk4  = (tid & 15) * 4;
  const int wrow = tid >> 3;            // 8 threads/row, 32 rows/pass
  const int wk8  = (tid & 7) * 8;

  for (int kc = 0; kc < 4; ++kc){
    const int k0 = kc * 64;
    // stage x tile (gather sorted rows, fp32 -> bf16)
    #pragma unroll
    for (int p = 0; p < 4; ++p){
      int row = p * 16 + xrow;
      const float* src = x + (size_t)ord_s[row] * 256 + k0 + xk4;
      f32x4 v = *(const f32x4*)src;
      bf16x4 b;
      b[0] = f2bf(v[0]); b[1] = f2bf(v[1]); b[2] = f2bf(v[2]); b[3] = f2bf(v[3]);
      *(bf16x4*)&sm.st.xs[row][xk4] = b;
    }
    // stage Wf/Wg tiles (already bf16)
    #pragma unroll
    for (int p = 0; p < 4; ++p){
      int row = p * 32 + wrow;
      *(i32x4*)&sm.st.ws[0][row][wk8] = *(const i32x4*)(wfb + (size_t)(j0 + row) * 256 + k0 + wk8);
      *(i32x4*)&sm.st.ws[1][row][wk8] = *(const i32x4*)(wgb + (size_t)(j0 + row) * 256 + k0 + wk8);
    }
    __syncthreads();
    #pragma unroll
    for (int ks = 0; ks < 2; ++ks){
      bf16x8 a = *(const bf16x8*)&sm.st.xs[wave * 16 + l16][ks * 32 + quad * 8];
      #pragma unroll
      for (int t = 0; t < 8; ++t){
        bf16x8 bF = *(const bf16x8*)&sm.st.ws[0][t * 16 + l16][ks * 32 + quad * 8];
        accF[t] = __builtin_amdgcn_mfma_f32_16x16x32_bf16(a, bF, accF[t], 0, 0, 0);
        bf16x8 bG = *(const bf16x8*)&sm.st.ws[1][t * 16 + l16][ks * 32 + quad * 8];
        accG[t] = __builtin_amdgcn_mfma_f32_16x16x32_bf16(a, bG, accG[t], 0, 0, 0);
      }
    }
    __syncthreads();
  }

  // biases for this lane's columns
  float bfr[8], bgr[8];
  #pragma unroll
  for (int t = 0; t < 8; ++t){
    bfr[t] = bf[j0 + t * 16 + l16];
    bgr[t] = bg[j0 + t * 16 + l16];
  }

  // epilogue: two 32-row halves through LDS, run-length segmented reduce
  #pragma unroll 1
  for (int half = 0; half < 2; ++half){
    __syncthreads();
    if ((wave >> 1) == half){
      int rbase = (wave & 1) * 16 + quad * 4;   // row within half
      #pragma unroll
      for (int t = 0; t < 8; ++t){
        #pragma unroll
        for (int r = 0; r < 4; ++r){
          int row = rbase + r;
          float f = accF[t][r] + bfr[t];
          float g = accG[t][r] + bgr[t];
          g = fminf(fmaxf(g, -50.f), 50.f);
          float e = __expf(g);
          sm.ep.ps[row][t * 16 + l16] = f * e;
          sm.ep.es[row][t * 16 + l16] = e;
        }
      }
    }
    __syncthreads();
    int col = tid & 127;
    int seg = tid >> 7;                 // 2 row-segments of 16
    int gbase = half * 32 + seg * 16;
    float ns = 0.f, ds = 0.f;
    int curg = gid_s[gbase];
    #pragma unroll 1
    for (int rr = 0; rr < 16; ++rr){
      int g = gid_s[gbase + rr];
      if (g != curg){
        atomicAdd(&numer[(size_t)curg * 256 + j0 + col], ns);
        atomicAdd(&denom[(size_t)curg * 256 + j0 + col], ds);
        ns = 0.f; ds = 0.f; curg = g;
      }
      int lrow = seg * 16 + rr;
      ns += sm.ep.ps[lrow][col];
      ds += sm.ep.es[lrow][col];
    }
    atomicAdd(&numer[(size_t)curg * 256 + j0 + col], ns);
    atomicAdd(&denom[(size_t)curg * 256 + j0 + col], ds);
  }
}

// ---- yh[g] = (numer[g]/denom[g]) @ Wh.T + bh ----
__global__ __launch_bounds__(256) void k_yh(
    const float* __restrict__ numer, const float* __restrict__ denom,
    const float* __restrict__ wht, const float* __restrict__ bh,
    float* __restrict__ yh)
{
  __shared__ float ys[16][256];
  int t = threadIdx.x;
  int g0 = blockIdx.x * 16;
  #pragma unroll
  for (int gg = 0; gg < 16; ++gg){
    size_t idx = (size_t)(g0 + gg) * 256 + t;
    float d = denom[idx];
    ys[gg][t] = (d != 0.f) ? (numer[idx] / d) : 0.f;
  }
  __syncthreads();
  float acc[16];
  #pragma unroll
  for (int gg = 0; gg < 16; ++gg) acc[gg] = 0.f;
  for (int k = 0; k < 256; ++k){
    float wt = wht[k * 256 + t];        // coalesced; wht L2-resident
    #pragma unroll
    for (int gg = 0; gg < 16; ++gg) acc[gg] += wt * ys[gg][k];  // LDS broadcast
  }
  float b = bh[t];
  #pragma unroll
  for (int gg = 0; gg < 16; ++gg) yh[(size_t)(g0 + gg) * 256 + t] = acc[gg] + b;
}

// ---- out[i] = yh[ix[i]] ----
__global__ __launch_bounds__(256) void k_out(const int* __restrict__ ix,
    const float* __restrict__ yh, float* __restrict__ out)
{
  int wave = threadIdx.x >> 6;
  int lane = threadIdx.x & 63;
  int i = blockIdx.x * 4 + wave;
  int stride = gridDim.x * 4;
  for (; i < N_ROWS; i += stride){
    int g = ix[i];
    f32x4 v = *(const f32x4*)(yh + (size_t)g * 256 + lane * 4);
    *(f32x4*)(out + (size_t)i * 256 + lane * 4) = v;
  }
}

extern "C" void kernel_launch(void* const* d_in, const int* in_sizes, int n_in,
                              void* d_out, int out_size, void* d_ws, size_t ws_size,
                              hipStream_t stream)
{
  const float* x  = (const float*)d_in[0];
  const float* Wf = (const float*)d_in[1];
  const float* bf = (const float*)d_in[2];
  const float* Wg = (const float*)d_in[3];
  const float* bg = (const float*)d_in[4];
  const float* Wh = (const float*)d_in[5];
  const float* bh = (const float*)d_in[6];
  const int*   ix = (const int*)d_in[7];
  float* out = (float*)d_out;

  char* ws = (char*)d_ws;
  // layout (bytes):
  float* numer  = (float*)(ws + 0);          // 4 MiB
  float* denom  = (float*)(ws + 4194304);    // 4 MiB
  int*   counts = (int*)  (ws + 8388608);    // 16 KiB
  int*   cursor = (int*)  (ws + 8404992);    // 16 KiB
  float* yh     = (float*)(ws + 8421376);    // 4 MiB
  float* wht    = (float*)(ws + 12615680);   // 256 KiB
  short* wfb    = (short*)(ws + 12877824);   // 128 KiB
  short* wgb    = (short*)(ws + 13008896);   // 128 KiB
  int*   order  = (int*)  (ws + 13139968);   // 1 MiB
  int*   gid    = (int*)  (ws + 14188544);   // 1 MiB  (end ~14.5 MiB)

  hipMemsetAsync(ws, 0, 8404992, stream);    // numer + denom + counts

  k_castw<<<256, 256, 0, stream>>>(Wf, Wg, Wh, wfb, wgb, wht);
  k_hist<<<512, 256, 0, stream>>>(ix, counts);
  k_scan<<<1, 1024, 0, stream>>>(counts, cursor);
  k_scatter<<<512, 256, 0, stream>>>(ix, cursor, order, gid);
  dim3 ggrid(4096, 2);
  k_gemm<<<ggrid, 256, 0, stream>>>(x, wfb, wgb, bf, bg, order, gid, numer, denom);
  k_yh<<<256, 256, 0, stream>>>(numer, denom, wht, bh, yh);
  k_out<<<2048, 256, 0, stream>>>(ix, yh, out);
}

// Round 2
// 854.147 us; speedup vs baseline: 1.0289x; 1.0289x over previous
//
#include <hip/hip_runtime.h>
#include <stdint.h>
#include <stddef.h>

#define N_ROWS 262144
#define CCH    256
#define NGRP   4096

typedef short bf16x8 __attribute__((ext_vector_type(8)));
typedef short bf16x4 __attribute__((ext_vector_type(4)));
typedef float f32x4  __attribute__((ext_vector_type(4)));
typedef int   i32x4  __attribute__((ext_vector_type(4)));

static __device__ __forceinline__ short f2bf(float f){
  union { float f; unsigned u; } v; v.f = f;
  unsigned u = v.u;
  unsigned r = (u + 0x7FFFu + ((u >> 16) & 1u)) >> 16;   // round-to-nearest-even
  return (short)r;
}

typedef __attribute__((address_space(1))) const unsigned int GU32;
typedef __attribute__((address_space(3))) unsigned int LU32;
static __device__ __forceinline__ void gload_lds16(const void* g, void* l){
  __builtin_amdgcn_global_load_lds((GU32*)g, (LU32*)l, 16, 0, 0);
}

// ---- cast Wf/Wg to bf16; build Wh transpose (wht[k][j] = Wh[j][k]) ----
__global__ __launch_bounds__(256) void k_castw(
    const float* __restrict__ Wf, const float* __restrict__ Wg,
    const float* __restrict__ Wh,
    short* __restrict__ wfb, short* __restrict__ wgb, float* __restrict__ wht)
{
  int e = blockIdx.x * 256 + threadIdx.x;           // 65536 exact
  wfb[e] = f2bf(Wf[e]);
  wgb[e] = f2bf(Wg[e]);
  int k = e >> 8, j = e & 255;
  wht[e] = Wh[j * 256 + k];
}

// ---- histogram of group ids ----
__global__ __launch_bounds__(256) void k_hist(const int* __restrict__ ix, int* __restrict__ counts){
  int i = blockIdx.x * blockDim.x + threadIdx.x;
  int stride = gridDim.x * blockDim.x;
  for (; i < N_ROWS; i += stride) atomicAdd(&counts[ix[i]], 1);
}

// ---- exclusive prefix sum over 4096 counts -> cursor ----
__global__ __launch_bounds__(1024) void k_scan(const int* __restrict__ counts, int* __restrict__ cursor){
  __shared__ int sums[1024];
  int t = threadIdx.x;
  int base = t * 4;
  int c0 = counts[base], c1 = counts[base+1], c2 = counts[base+2], c3 = counts[base+3];
  sums[t] = c0 + c1 + c2 + c3;
  __syncthreads();
  for (int off = 1; off < 1024; off <<= 1){
    int v = (t >= off) ? sums[t - off] : 0;
    __syncthreads();
    sums[t] += v;
    __syncthreads();
  }
  int prev = (t == 0) ? 0 : sums[t - 1];
  cursor[base]   = prev;
  cursor[base+1] = prev + c0;
  cursor[base+2] = prev + c0 + c1;
  cursor[base+3] = prev + c0 + c1 + c2;
}

// ---- scatter: counting-sort row indices by group ----
__global__ __launch_bounds__(256) void k_scatter(const int* __restrict__ ix, int* __restrict__ cursor,
                                                 int* __restrict__ order, int* __restrict__ gid){
  int i = blockIdx.x * blockDim.x + threadIdx.x;
  int stride = gridDim.x * blockDim.x;
  for (; i < N_ROWS; i += stride){
    int g = ix[i];
    int p = atomicAdd(&cursor[g], 1);
    order[p] = i;
    gid[p] = g;
  }
}

// ---- fused GEMM (fx & gx) + exp + segment reduce ----
// block: 128 sorted rows x 128 cols; 4 waves, each 32 rows (2 row-frags).
// B staged in fragment-linear LDS via global_load_lds (conflict-free b128 reads).
// A loaded global->reg per wave (rows are wave-exclusive). Epilogue in registers.
__global__ __launch_bounds__(256) void k_gemm(
    const float* __restrict__ x,
    const short* __restrict__ wfb, const short* __restrict__ wgb,
    const float* __restrict__ bfp, const float* __restrict__ bgp,
    const int* __restrict__ order, const int* __restrict__ gid,
    float* __restrict__ numer, float* __restrict__ denom)
{
  __shared__ short bst[2][2][8][512];   // [matrix][ks][t][lane*8 bf16] = 32 KiB
  __shared__ int ord_s[128];
  __shared__ int gid_s[128];

  const int tid  = threadIdx.x;
  const int wave = tid >> 6;
  const int lane = tid & 63;
  const int l16  = lane & 15;
  const int quad = lane >> 4;

  const int r0 = blockIdx.x * 128;    // sorted-row base
  const int j0 = blockIdx.y * 128;    // output-column base

  if (tid < 128){ ord_s[tid] = order[r0 + tid]; gid_s[tid] = gid[r0 + tid]; }
  __syncthreads();

  const float* xr0 = x + (size_t)ord_s[wave * 32 + l16] * 256;
  const float* xr1 = x + (size_t)ord_s[wave * 32 + 16 + l16] * 256;

  // this wave stages: matrix sm, k-step sks, all 8 t-fragments
  const int sm  = wave >> 1;
  const int sks = wave & 1;
  const short* wsrc = sm ? wgb : wfb;
  const short* bsrc = wsrc + (size_t)(j0 + l16) * 256 + sks * 32 + quad * 8;

  f32x4 accF[2][8], accG[2][8];
  #pragma unroll
  for (int rg = 0; rg < 2; ++rg)
    #pragma unroll
    for (int t = 0; t < 8; ++t){
      accF[rg][t] = (f32x4){0.f,0.f,0.f,0.f};
      accG[rg][t] = (f32x4){0.f,0.f,0.f,0.f};
    }

  for (int kc = 0; kc < 4; ++kc){
    const int k0 = kc * 64;
    // stage B fragments (async, lane-linear LDS dest)
    #pragma unroll
    for (int t = 0; t < 8; ++t)
      gload_lds16(bsrc + (size_t)t * 16 * 256 + k0, &bst[sm][sks][t][0]);
    // A loads (fp32, 2 row-frags x 2 ks x 8 floats)
    f32x4 av[2][2][2];
    #pragma unroll
    for (int rg = 0; rg < 2; ++rg){
      const float* xp = (rg ? xr1 : xr0) + k0 + quad * 8;
      #pragma unroll
      for (int ks = 0; ks < 2; ++ks){
        av[rg][ks][0] = *(const f32x4*)(xp + ks * 32);
        av[rg][ks][1] = *(const f32x4*)(xp + ks * 32 + 4);
      }
    }
    __syncthreads();   // drains vmcnt: B in LDS + A in regs
    #pragma unroll
    for (int ks = 0; ks < 2; ++ks){
      bf16x8 a0, a1;
      #pragma unroll
      for (int j = 0; j < 4; ++j){
        a0[j]   = f2bf(av[0][ks][0][j]);
        a0[4+j] = f2bf(av[0][ks][1][j]);
        a1[j]   = f2bf(av[1][ks][0][j]);
        a1[4+j] = f2bf(av[1][ks][1][j]);
      }
      #pragma unroll
      for (int t = 0; t < 8; ++t){
        bf16x8 bFv = *(const bf16x8*)&bst[0][ks][t][lane * 8];
        accF[0][t] = __builtin_amdgcn_mfma_f32_16x16x32_bf16(a0, bFv, accF[0][t], 0, 0, 0);
        accF[1][t] = __builtin_amdgcn_mfma_f32_16x16x32_bf16(a1, bFv, accF[1][t], 0, 0, 0);
        bf16x8 bGv = *(const bf16x8*)&bst[1][ks][t][lane * 8];
        accG[0][t] = __builtin_amdgcn_mfma_f32_16x16x32_bf16(a0, bGv, accG[0][t], 0, 0, 0);
        accG[1][t] = __builtin_amdgcn_mfma_f32_16x16x32_bf16(a1, bGv, accG[1][t], 0, 0, 0);
      }
    }
    __syncthreads();   // protect bst before next stage
  }

  // ---- epilogue: bias + clamp + exp, in-register ----
  float bfr[8], bgr[8];
  #pragma unroll
  for (int t = 0; t < 8; ++t){
    bfr[t] = bfp[j0 + t * 16 + l16];
    bgr[t] = bgp[j0 + t * 16 + l16];
  }
  #pragma unroll
  for (int rg = 0; rg < 2; ++rg)
    #pragma unroll
    for (int t = 0; t < 8; ++t)
      #pragma unroll
      for (int r = 0; r < 4; ++r){
        float g = accG[rg][t][r] + bgr[t];
        g = fminf(fmaxf(g, -50.f), 50.f);
        float e = __expf(g);
        accF[rg][t][r] = (accF[rg][t][r] + bfr[t]) * e;   // f * e
        accG[rg][t][r] = e;                               // e
      }

  // ---- segmented reduction over this wave's 32 sorted rows ----
  const int base = wave * 32;
  const int qd4 = quad * 4;
  int start = 0;
  while (start < 32){
    int g = gid_s[base + start];
    int end = start + 1;
    while (end < 32 && gid_s[base + end] == g) ++end;
    #pragma unroll
    for (int t = 0; t < 8; ++t){
      float sF = 0.f, sE = 0.f;
      #pragma unroll
      for (int rg = 0; rg < 2; ++rg)
        #pragma unroll
        for (int r = 0; r < 4; ++r){
          int rl = rg * 16 + qd4 + r;
          bool in = (rl >= start) && (rl < end);
          sF += in ? accF[rg][t][r] : 0.f;
          sE += in ? accG[rg][t][r] : 0.f;
        }
      sF += __shfl_xor(sF, 16); sF += __shfl_xor(sF, 32);
      sE += __shfl_xor(sE, 16); sE += __shfl_xor(sE, 32);
      if (quad == 0){
        atomicAdd(&numer[(size_t)g * 256 + j0 + t * 16 + l16], sF);
        atomicAdd(&denom[(size_t)g * 256 + j0 + t * 16 + l16], sE);
      }
    }
    start = end;
  }
}

// ---- yh[g] = (numer[g]/denom[g]) @ Wh.T + bh ----
__global__ __launch_bounds__(256) void k_yh(
    const float* __restrict__ numer, const float* __restrict__ denom,
    const float* __restrict__ wht, const float* __restrict__ bh,
    float* __restrict__ yh)
{
  __shared__ float ys[16][256];
  int t = threadIdx.x;
  int g0 = blockIdx.x * 16;
  #pragma unroll
  for (int gg = 0; gg < 16; ++gg){
    size_t idx = (size_t)(g0 + gg) * 256 + t;
    float d = denom[idx];
    ys[gg][t] = (d != 0.f) ? (numer[idx] / d) : 0.f;
  }
  __syncthreads();
  float acc[16];
  #pragma unroll
  for (int gg = 0; gg < 16; ++gg) acc[gg] = 0.f;
  for (int k = 0; k < 256; k += 4){
    float w0 = wht[(k+0) * 256 + t];
    float w1 = wht[(k+1) * 256 + t];
    float w2 = wht[(k+2) * 256 + t];
    float w3 = wht[(k+3) * 256 + t];
    #pragma unroll
    for (int gg = 0; gg < 16; ++gg)
      acc[gg] += w0 * ys[gg][k] + w1 * ys[gg][k+1] + w2 * ys[gg][k+2] + w3 * ys[gg][k+3];
  }
  float b = bh[t];
  #pragma unroll
  for (int gg = 0; gg < 16; ++gg) yh[(size_t)(g0 + gg) * 256 + t] = acc[gg] + b;
}

// ---- out[i] = yh[ix[i]] ----
__global__ __launch_bounds__(256) void k_out(const int* __restrict__ ix,
    const float* __restrict__ yh, float* __restrict__ out)
{
  int wave = threadIdx.x >> 6;
  int lane = threadIdx.x & 63;
  int i = blockIdx.x * 4 + wave;
  int stride = gridDim.x * 4;
  for (; i < N_ROWS; i += stride){
    int g = ix[i];
    f32x4 v = *(const f32x4*)(yh + (size_t)g * 256 + lane * 4);
    *(f32x4*)(out + (size_t)i * 256 + lane * 4) = v;
  }
}

extern "C" void kernel_launch(void* const* d_in, const int* in_sizes, int n_in,
                              void* d_out, int out_size, void* d_ws, size_t ws_size,
                              hipStream_t stream)
{
  const float* x  = (const float*)d_in[0];
  const float* Wf = (const float*)d_in[1];
  const float* bf = (const float*)d_in[2];
  const float* Wg = (const float*)d_in[3];
  const float* bg = (const float*)d_in[4];
  const float* Wh = (const float*)d_in[5];
  const float* bh = (const float*)d_in[6];
  const int*   ix = (const int*)d_in[7];
  float* out = (float*)d_out;

  char* ws = (char*)d_ws;
  float* numer  = (float*)(ws + 0);          // 4 MiB
  float* denom  = (float*)(ws + 4194304);    // 4 MiB
  int*   counts = (int*)  (ws + 8388608);    // 16 KiB
  int*   cursor = (int*)  (ws + 8404992);    // 16 KiB
  float* yh     = (float*)(ws + 8421376);    // 4 MiB
  float* wht    = (float*)(ws + 12615680);   // 256 KiB
  short* wfb    = (short*)(ws + 12877824);   // 128 KiB
  short* wgb    = (short*)(ws + 13008896);   // 128 KiB
  int*   order  = (int*)  (ws + 13139968);   // 1 MiB
  int*   gid    = (int*)  (ws + 14188544);   // 1 MiB

  hipMemsetAsync(ws, 0, 8404992, stream);    // numer + denom + counts

  k_castw<<<256, 256, 0, stream>>>(Wf, Wg, Wh, wfb, wgb, wht);
  k_hist<<<512, 256, 0, stream>>>(ix, counts);
  k_scan<<<1, 1024, 0, stream>>>(counts, cursor);
  k_scatter<<<512, 256, 0, stream>>>(ix, cursor, order, gid);
  dim3 ggrid(2048, 2);
  k_gemm<<<ggrid, 256, 0, stream>>>(x, wfb, wgb, bf, bg, order, gid, numer, denom);
  k_yh<<<256, 256, 0, stream>>>(numer, denom, wht, bh, yh);
  k_out<<<2048, 256, 0, stream>>>(ix, yh, out);
}